// Round 1
// 1272.968 us; speedup vs baseline: 1.0215x; 1.0215x over previous
//
#include <hip/hip_runtime.h>
#include <hip/hip_bf16.h>

#define C 64  // channels

// bf16 <-> f32 helpers (bit-level, RNE on pack)
__device__ __forceinline__ float b2f(unsigned short s) {
    return __uint_as_float(((unsigned int)s) << 16);
}
__device__ __forceinline__ unsigned short f2b(float f) {
    unsigned int u = __float_as_uint(f);
    u = (u + 0x7FFF + ((u >> 16) & 1)) >> 16;
    return (unsigned short)u;
}
__device__ __forceinline__ float4 bf4(ushort4 u) {
    return make_float4(b2f(u.x), b2f(u.y), b2f(u.z), b2f(u.w));
}

// ---------------------------------------------------------------------------
// Fused MLP: h = relu(relu(x @ W1) @ W2).
// Writes BOTH fp32 h0 (hop-0 gate) and bf16 hb (propagation seed).
// R5: BK=64 (8 K-iters, 2 barriers each) + register-prefetch pipeline:
//   commit regs->LDS, barrier, ISSUE next-tile global loads, compute 1024
//   FMAs on current tile (hides ~900cy HBM latency), barrier, repeat.
// Same 64x64 tile, pad-68 conflict-free layout, 34816B LDS (4 blocks/CU).
// ---------------------------------------------------------------------------
__launch_bounds__(256)
__global__ void mlp_kernel(const float* __restrict__ x,
                           const float* __restrict__ W1,
                           const float* __restrict__ W2,
                           float* __restrict__ h0,
                           unsigned short* __restrict__ hb, int nN)
{
    __shared__ float smem[8704];
    float (*As)[68] = (float(*)[68])smem;            // 64 x 68 = 4352 floats
    float (*Bs)[68] = (float(*)[68])(smem + 4352);   // 64 x 68 = 4352 floats
    float (*Hs)[68] = (float(*)[68])smem;            // GEMM2 reuse
    float (*Ws)[68] = (float(*)[68])(smem + 4352);

    const int t  = threadIdx.x;
    const int ty = t >> 4;
    const int tx = t & 15;
    const int row0 = blockIdx.x * 64;

    // staging map (BK=64): f = t + 256h -> row/kr = (t>>4)+16h, col = (t&15)*4
    const int srow = t >> 4;
    const int slk  = (t & 15) * 4;

    float4 ar[4], br[4];

    // prologue: load tile k0=0 into regs
    #pragma unroll
    for (int h = 0; h < 4; ++h) {
        int r = srow + 16 * h;
        int grow = row0 + r;
        ar[h] = make_float4(0.f, 0.f, 0.f, 0.f);
        if (grow < nN) ar[h] = *(const float4*)&x[(size_t)grow * 512 + slk];
        br[h] = *(const float4*)&W1[(size_t)r * 64 + slk];
    }

    float acc[4][4] = {};

    for (int k0 = 0; k0 < 512; k0 += 64) {
        // commit staged regs -> LDS
        #pragma unroll
        for (int h = 0; h < 4; ++h) {
            int r = srow + 16 * h;
            *(float4*)&As[r][slk] = ar[h];
            *(float4*)&Bs[r][slk] = br[h];
        }
        __syncthreads();

        // issue next-tile global loads (consumed only at next commit)
        if (k0 + 64 < 512) {
            const int kn = k0 + 64;
            #pragma unroll
            for (int h = 0; h < 4; ++h) {
                int r = srow + 16 * h;
                int grow = row0 + r;
                ar[h] = make_float4(0.f, 0.f, 0.f, 0.f);
                if (grow < nN) ar[h] = *(const float4*)&x[(size_t)grow * 512 + kn + slk];
                br[h] = *(const float4*)&W1[(size_t)(kn + r) * 64 + slk];
            }
        }

        // 1024 FMAs on current tile
        for (int kk = 0; kk < 64; kk += 4) {
            float4 b0 = *(float4*)&Bs[kk + 0][tx * 4];
            float4 b1 = *(float4*)&Bs[kk + 1][tx * 4];
            float4 b2 = *(float4*)&Bs[kk + 2][tx * 4];
            float4 b3 = *(float4*)&Bs[kk + 3][tx * 4];
            #pragma unroll
            for (int i = 0; i < 4; ++i) {
                float4 a = *(float4*)&As[ty * 4 + i][kk];
                acc[i][0] += a.x * b0.x + a.y * b1.x + a.z * b2.x + a.w * b3.x;
                acc[i][1] += a.x * b0.y + a.y * b1.y + a.z * b2.y + a.w * b3.y;
                acc[i][2] += a.x * b0.z + a.y * b1.z + a.z * b2.z + a.w * b3.z;
                acc[i][3] += a.x * b0.w + a.y * b1.w + a.z * b2.w + a.w * b3.w;
            }
        }
        __syncthreads();
    }

    // ReLU -> Hs (reuses As region; last barrier guarantees compute done)
    #pragma unroll
    for (int i = 0; i < 4; ++i) {
        float4 o;
        o.x = acc[i][0] > 0.f ? acc[i][0] : 0.f;
        o.y = acc[i][1] > 0.f ? acc[i][1] : 0.f;
        o.z = acc[i][2] > 0.f ? acc[i][2] : 0.f;
        o.w = acc[i][3] > 0.f ? acc[i][3] : 0.f;
        *(float4*)&Hs[ty * 4 + i][tx * 4] = o;
    }
    #pragma unroll
    for (int q = 0; q < 4; ++q) {
        int r = srow + 16 * q;
        *(float4*)&Ws[r][slk] = *(const float4*)&W2[(size_t)r * 64 + slk];
    }
    __syncthreads();

    float acc2[4][4] = {};
    for (int kk = 0; kk < 64; kk += 4) {
        float4 b0 = *(float4*)&Ws[kk + 0][tx * 4];
        float4 b1 = *(float4*)&Ws[kk + 1][tx * 4];
        float4 b2 = *(float4*)&Ws[kk + 2][tx * 4];
        float4 b3 = *(float4*)&Ws[kk + 3][tx * 4];
        #pragma unroll
        for (int i = 0; i < 4; ++i) {
            float4 a = *(float4*)&Hs[ty * 4 + i][kk];
            acc2[i][0] += a.x * b0.x + a.y * b1.x + a.z * b2.x + a.w * b3.x;
            acc2[i][1] += a.x * b0.y + a.y * b1.y + a.z * b2.y + a.w * b3.y;
            acc2[i][2] += a.x * b0.z + a.y * b1.z + a.z * b2.z + a.w * b3.z;
            acc2[i][3] += a.x * b0.w + a.y * b1.w + a.z * b2.w + a.w * b3.w;
        }
    }

    #pragma unroll
    for (int i = 0; i < 4; ++i) {
        int grow = row0 + ty * 4 + i;
        if (grow < nN) {
            float4 o;
            o.x = acc2[i][0] > 0.f ? acc2[i][0] : 0.f;
            o.y = acc2[i][1] > 0.f ? acc2[i][1] : 0.f;
            o.z = acc2[i][2] > 0.f ? acc2[i][2] : 0.f;
            o.w = acc2[i][3] > 0.f ? acc2[i][3] : 0.f;
            *(float4*)&h0[(size_t)grow * 64 + tx * 4] = o;
            ushort4 ob = make_ushort4(f2b(o.x), f2b(o.y), f2b(o.z), f2b(o.w));
            *(ushort4*)&hb[(size_t)grow * 64 + tx * 4] = ob;
        }
    }
}

// ---------------------------------------------------------------------------
// CSR build: degree count -> single-block scan -> atomic fill (packed col+wgt).
// After fill, rowptr[n] = END offset; start = rowptr[n-1] (0 for n=0).
// ---------------------------------------------------------------------------
__launch_bounds__(256)
__global__ void count_kernel(const int* __restrict__ dst, int* __restrict__ rowptr, int nE)
{
    int e = blockIdx.x * 256 + threadIdx.x;
    if (e < nE) atomicAdd(&rowptr[dst[e]], 1);
}

__launch_bounds__(1024)
__global__ void scan_kernel(int* __restrict__ deg, int nN)
{
    __shared__ int sums[1024];
    const int t = threadIdx.x;
    const int len = (nN + 1023) / 1024;
    const int lo = t * len;
    const int hi = min(nN, lo + len);
    int s = 0;
    for (int i = lo; i < hi; ++i) s += deg[i];
    sums[t] = s;
    __syncthreads();
    for (int d = 1; d < 1024; d <<= 1) {
        int v = (t >= d) ? sums[t - d] : 0;
        __syncthreads();
        sums[t] += v;
        __syncthreads();
    }
    int off = sums[t] - s;
    for (int i = lo; i < hi; ++i) {
        int d = deg[i];
        deg[i] = off;
        off += d;
    }
}

__launch_bounds__(256)
__global__ void fill_kernel(const int* __restrict__ src, const int* __restrict__ dst,
                            const float* __restrict__ w,
                            int* __restrict__ rowptr,
                            int2* __restrict__ cwp, int nE)
{
    int e = blockIdx.x * 256 + threadIdx.x;
    if (e >= nE) return;
    int d = dst[e];
    int pos = atomicAdd(&rowptr[d], 1);
    cwp[pos] = make_int2(src[e], __float_as_int(w[e]));
}

// ---------------------------------------------------------------------------
// Fused pull-SpMM + gate, bf16 propagation.  One wave per dst node (or per
// output index).  4 edge groups x 16 lanes x ushort4 (8B = 4 bf16 ch each);
// 4 edges unrolled per group = 16 edges in flight.  fp32 accumulate.
// Node blocks write bf16 nxt; idx-tail blocks gate fp32 row into out.
// ---------------------------------------------------------------------------
__launch_bounds__(256)
__global__ void spmm_fused(const int* __restrict__ rowptr,
                           const int2* __restrict__ cwp,
                           const unsigned short* __restrict__ cur,
                           unsigned short* __restrict__ nxt,
                           const int* __restrict__ idx,
                           const float* __restrict__ wp,
                           float* __restrict__ out,
                           int nN, int nI, int nodeBlocks)
{
    const int bid  = blockIdx.x;
    const int wid  = threadIdx.x >> 6;
    const int lane = threadIdx.x & 63;
    const int g = lane >> 4;   // edge sub-slot 0..3
    const int q = lane & 15;   // channel quad

    int node, oi = -1;
    if (bid < nodeBlocks) {
        node = bid * 4 + wid;
        if (node >= nN) return;
    } else {
        oi = (bid - nodeBlocks) * 4 + wid;
        if (oi >= nI) return;
        node = idx[oi];
    }

    const int beg = (node == 0) ? 0 : rowptr[node - 1];
    const int end = rowptr[node];

    float4 A0 = make_float4(0.f,0.f,0.f,0.f);
    float4 A1 = make_float4(0.f,0.f,0.f,0.f);
    float4 A2 = make_float4(0.f,0.f,0.f,0.f);
    float4 A3 = make_float4(0.f,0.f,0.f,0.f);

    int e = beg + g;
    for (; e + 12 < end; e += 16) {
        int2 c0 = cwp[e];
        int2 c1 = cwp[e + 4];
        int2 c2 = cwp[e + 8];
        int2 c3 = cwp[e + 12];
        float4 v0 = bf4(*(const ushort4*)&cur[(size_t)c0.x * 64 + q * 4]);
        float4 v1 = bf4(*(const ushort4*)&cur[(size_t)c1.x * 64 + q * 4]);
        float4 v2 = bf4(*(const ushort4*)&cur[(size_t)c2.x * 64 + q * 4]);
        float4 v3 = bf4(*(const ushort4*)&cur[(size_t)c3.x * 64 + q * 4]);
        float w0 = __int_as_float(c0.y), w1 = __int_as_float(c1.y);
        float w2 = __int_as_float(c2.y), w3 = __int_as_float(c3.y);
        A0.x += w0*v0.x; A0.y += w0*v0.y; A0.z += w0*v0.z; A0.w += w0*v0.w;
        A1.x += w1*v1.x; A1.y += w1*v1.y; A1.z += w1*v1.z; A1.w += w1*v1.w;
        A2.x += w2*v2.x; A2.y += w2*v2.y; A2.z += w2*v2.z; A2.w += w2*v2.w;
        A3.x += w3*v3.x; A3.y += w3*v3.y; A3.z += w3*v3.z; A3.w += w3*v3.w;
    }
    for (; e < end; e += 4) {
        int2 c0 = cwp[e];
        float4 v0 = bf4(*(const ushort4*)&cur[(size_t)c0.x * 64 + q * 4]);
        float w0 = __int_as_float(c0.y);
        A0.x += w0*v0.x; A0.y += w0*v0.y; A0.z += w0*v0.z; A0.w += w0*v0.w;
    }
    A0.x += A1.x + A2.x + A3.x;
    A0.y += A1.y + A2.y + A3.y;
    A0.z += A1.z + A2.z + A3.z;
    A0.w += A1.w + A2.w + A3.w;

    // reduce across the 4 edge groups (lanes differing in bits 4,5)
    A0.x += __shfl_xor(A0.x, 16); A0.y += __shfl_xor(A0.y, 16);
    A0.z += __shfl_xor(A0.z, 16); A0.w += __shfl_xor(A0.w, 16);
    A0.x += __shfl_xor(A0.x, 32); A0.y += __shfl_xor(A0.y, 32);
    A0.z += __shfl_xor(A0.z, 32); A0.w += __shfl_xor(A0.w, 32);

    if (oi < 0) {
        if (g == 0) {
            ushort4 ob = make_ushort4(f2b(A0.x), f2b(A0.y), f2b(A0.z), f2b(A0.w));
            *(ushort4*)&nxt[(size_t)node * 64 + q * 4] = ob;
        }
    } else {
        // gate: s = row . wp  (reduce partial dot across the 16 q-lanes)
        float s = A0.x * wp[q * 4] + A0.y * wp[q * 4 + 1]
                + A0.z * wp[q * 4 + 2] + A0.w * wp[q * 4 + 3];
        s += __shfl_xor(s, 1); s += __shfl_xor(s, 2);
        s += __shfl_xor(s, 4); s += __shfl_xor(s, 8);
        float gate = 1.f / (1.f + __expf(-s));
        if (g == 0) {
            float* op = &out[(size_t)oi * 64 + q * 4];
            float4 prev = *(float4*)op;
            prev.x += gate * A0.x; prev.y += gate * A0.y;
            prev.z += gate * A0.z; prev.w += gate * A0.w;
            *(float4*)op = prev;
        }
    }
}

// ---------------------------------------------------------------------------
// Hop-0 gate: out[i] = sigmoid(h[idx[i]].wp) * h[idx[i]]  (fp32 h, inits out)
// ---------------------------------------------------------------------------
__launch_bounds__(256)
__global__ void gate_gather(const float* __restrict__ h,
                            const int* __restrict__ idx,
                            const float* __restrict__ wp,
                            float* __restrict__ out, int nI)
{
    int gid = blockIdx.x * 256 + threadIdx.x;
    int i = gid >> 6;
    if (i >= nI) return;
    int c = gid & 63;
    int n = idx[i];
    float v = h[(size_t)n * 64 + c];
    float s = v * wp[c];
    #pragma unroll
    for (int off = 32; off > 0; off >>= 1)
        s += __shfl_xor(s, off);
    float gate = 1.f / (1.f + __expf(-s));
    out[gid] = gate * v;
}

extern "C" void kernel_launch(void* const* d_in, const int* in_sizes, int n_in,
                              void* d_out, int out_size, void* d_ws, size_t ws_size,
                              hipStream_t stream) {
    const float* x    = (const float*)d_in[0];
    const int*   esrc = (const int*)d_in[1];
    const int*   edst = (const int*)d_in[2];
    const float* ew   = (const float*)d_in[3];
    const int*   nidx = (const int*)d_in[4];
    const float* W1   = (const float*)d_in[5];
    const float* W2   = (const float*)d_in[6];
    const float* wp   = (const float*)d_in[7];
    float* out = (float*)d_out;

    const int nN = in_sizes[0] / 512;
    const int nE = in_sizes[1];
    const int nI = in_sizes[4];

    // ws: h0 fp32 25.6M | bufA bf16 12.8M | bufB bf16 12.8M | rowptr 0.4M | cwp 12.8M
    float*          h0     = (float*)d_ws;
    unsigned short* bufA   = (unsigned short*)(h0 + (size_t)nN * C);
    unsigned short* bufB   = bufA + (size_t)nN * C;
    int*            rowptr = (int*)(bufB + (size_t)nN * C);
    int2*           cwp    = (int2*)(rowptr + nN);

    // --- CSR build (by dst) ---
    hipMemsetAsync(rowptr, 0, (size_t)nN * sizeof(int), stream);
    count_kernel<<<(nE + 255) / 256, 256, 0, stream>>>(edst, rowptr, nE);
    scan_kernel<<<1, 1024, 0, stream>>>(rowptr, nN);
    fill_kernel<<<(nE + 255) / 256, 256, 0, stream>>>(esrc, edst, ew, rowptr, cwp, nE);

    // --- MLP (fp32 + bf16 h) ---
    mlp_kernel<<<(nN + 63) / 64, 256, 0, stream>>>(x, W1, W2, h0, bufA, nN);

    // hop 0 gate (initializes out, fp32 path)
    gate_gather<<<(nI * 64 + 255) / 256, 256, 0, stream>>>(h0, nidx, wp, out, nI);

    unsigned short* cur = bufA;
    unsigned short* nxt = bufB;
    const int nodeBlocks = (nN + 3) / 4;
    const int idxBlocks  = (nI + 3) / 4;
    for (int k = 0; k < 10; ++k) {
        // Final hop: nxt is never read again -> launch only the idx-tail
        // blocks (gate into out); skip the 25k node blocks entirely.
        const int nb = (k == 9) ? 0 : nodeBlocks;
        spmm_fused<<<nb + idxBlocks, 256, 0, stream>>>(
            rowptr, cwp, cur, nxt, nidx, wp, out, nN, nI, nb);
        unsigned short* tmp = cur; cur = nxt; nxt = tmp;
    }
}

// Round 4
// 1085.650 us; speedup vs baseline: 1.1977x; 1.1725x over previous
//
#include <hip/hip_runtime.h>
#include <hip/hip_bf16.h>

#define C 64  // channels

// bf16 <-> f32 helpers (bit-level, RNE on pack)
__device__ __forceinline__ float b2f(unsigned short s) {
    return __uint_as_float(((unsigned int)s) << 16);
}
__device__ __forceinline__ unsigned short f2b(float f) {
    unsigned int u = __float_as_uint(f);
    u = (u + 0x7FFF + ((u >> 16) & 1)) >> 16;
    return (unsigned short)u;
}
__device__ __forceinline__ float4 bf4(ushort4 u) {
    return make_float4(b2f(u.x), b2f(u.y), b2f(u.z), b2f(u.w));
}

// ---------------------------------------------------------------------------
// Fused MLP: h = relu(relu(x @ W1) @ W2).
// Writes BOTH fp32 h0 (hop-0 gate) and bf16 hb (propagation seed).
// BK=64 single-buffered, direct global->LDS staging (NO long-lived
// prefetch registers -- R1's reg-prefetch spilled to scratch: VGPR 92->68,
// WRITE_SIZE 37.5->190MB). 8 staging loads/thread/iter back-to-back gives
// 8-deep MLP; 8 iters x 2 barriers = half of R0's barrier count.
// Pad-68 layout: all LDS reads/writes 2-way or better (free).
// ---------------------------------------------------------------------------
__launch_bounds__(256)
__global__ void mlp_kernel(const float* __restrict__ x,
                           const float* __restrict__ W1,
                           const float* __restrict__ W2,
                           float* __restrict__ h0,
                           unsigned short* __restrict__ hb, int nN)
{
    __shared__ float smem[8704];
    float (*As)[68] = (float(*)[68])smem;            // 64 x 68
    float (*Bs)[68] = (float(*)[68])(smem + 4352);   // 64 x 68
    float (*Hs)[68] = (float(*)[68])smem;            // GEMM2 reuse
    float (*Ws)[68] = (float(*)[68])(smem + 4352);

    const int t  = threadIdx.x;
    const int ty = t >> 4;
    const int tx = t & 15;
    const int row0 = blockIdx.x * 64;

    // staging map: f = t + 256h -> row/kr = (t>>4)+16h, col = (t&15)*4
    const int srow = t >> 4;
    const int slk  = (t & 15) * 4;

    float acc[4][4] = {};

    for (int k0 = 0; k0 < 512; k0 += 64) {
        #pragma unroll
        for (int h = 0; h < 4; ++h) {
            int r = srow + 16 * h;
            int grow = row0 + r;
            float4 v = make_float4(0.f, 0.f, 0.f, 0.f);
            if (grow < nN) v = *(const float4*)&x[(size_t)grow * 512 + k0 + slk];
            *(float4*)&As[r][slk] = v;
        }
        #pragma unroll
        for (int h = 0; h < 4; ++h) {
            int r = srow + 16 * h;
            *(float4*)&Bs[r][slk] = *(const float4*)&W1[(size_t)(k0 + r) * 64 + slk];
        }
        __syncthreads();

        for (int kk = 0; kk < 64; kk += 4) {
            float4 b0 = *(float4*)&Bs[kk + 0][tx * 4];
            float4 b1 = *(float4*)&Bs[kk + 1][tx * 4];
            float4 b2 = *(float4*)&Bs[kk + 2][tx * 4];
            float4 b3 = *(float4*)&Bs[kk + 3][tx * 4];
            #pragma unroll
            for (int i = 0; i < 4; ++i) {
                float4 a = *(float4*)&As[ty * 4 + i][kk];
                acc[i][0] += a.x * b0.x + a.y * b1.x + a.z * b2.x + a.w * b3.x;
                acc[i][1] += a.x * b0.y + a.y * b1.y + a.z * b2.y + a.w * b3.y;
                acc[i][2] += a.x * b0.z + a.y * b1.z + a.z * b2.z + a.w * b3.z;
                acc[i][3] += a.x * b0.w + a.y * b1.w + a.z * b2.w + a.w * b3.w;
            }
        }
        __syncthreads();
    }

    // ReLU -> Hs (reuses As region; last barrier guarantees compute done)
    #pragma unroll
    for (int i = 0; i < 4; ++i) {
        float4 o;
        o.x = acc[i][0] > 0.f ? acc[i][0] : 0.f;
        o.y = acc[i][1] > 0.f ? acc[i][1] : 0.f;
        o.z = acc[i][2] > 0.f ? acc[i][2] : 0.f;
        o.w = acc[i][3] > 0.f ? acc[i][3] : 0.f;
        *(float4*)&Hs[ty * 4 + i][tx * 4] = o;
    }
    #pragma unroll
    for (int q = 0; q < 4; ++q) {
        int r = srow + 16 * q;
        *(float4*)&Ws[r][slk] = *(const float4*)&W2[(size_t)r * 64 + slk];
    }
    __syncthreads();

    float acc2[4][4] = {};
    for (int kk = 0; kk < 64; kk += 4) {
        float4 b0 = *(float4*)&Ws[kk + 0][tx * 4];
        float4 b1 = *(float4*)&Ws[kk + 1][tx * 4];
        float4 b2 = *(float4*)&Ws[kk + 2][tx * 4];
        float4 b3 = *(float4*)&Ws[kk + 3][tx * 4];
        #pragma unroll
        for (int i = 0; i < 4; ++i) {
            float4 a = *(float4*)&Hs[ty * 4 + i][kk];
            acc2[i][0] += a.x * b0.x + a.y * b1.x + a.z * b2.x + a.w * b3.x;
            acc2[i][1] += a.x * b0.y + a.y * b1.y + a.z * b2.y + a.w * b3.y;
            acc2[i][2] += a.x * b0.z + a.y * b1.z + a.z * b2.z + a.w * b3.z;
            acc2[i][3] += a.x * b0.w + a.y * b1.w + a.z * b2.w + a.w * b3.w;
        }
    }

    #pragma unroll
    for (int i = 0; i < 4; ++i) {
        int grow = row0 + ty * 4 + i;
        if (grow < nN) {
            float4 o;
            o.x = acc2[i][0] > 0.f ? acc2[i][0] : 0.f;
            o.y = acc2[i][1] > 0.f ? acc2[i][1] : 0.f;
            o.z = acc2[i][2] > 0.f ? acc2[i][2] : 0.f;
            o.w = acc2[i][3] > 0.f ? acc2[i][3] : 0.f;
            *(float4*)&h0[(size_t)grow * 64 + tx * 4] = o;
            ushort4 ob = make_ushort4(f2b(o.x), f2b(o.y), f2b(o.z), f2b(o.w));
            *(ushort4*)&hb[(size_t)grow * 64 + tx * 4] = ob;
        }
    }
}

// ---------------------------------------------------------------------------
// CSR build: degree count -> single-block scan -> atomic fill (packed col+wgt).
// After fill, rowptr[n] = END offset; start = rowptr[n-1] (0 for n=0).
// ---------------------------------------------------------------------------
__launch_bounds__(256)
__global__ void count_kernel(const int* __restrict__ dst, int* __restrict__ rowptr, int nE)
{
    int e = blockIdx.x * 256 + threadIdx.x;
    if (e < nE) atomicAdd(&rowptr[dst[e]], 1);
}

__launch_bounds__(1024)
__global__ void scan_kernel(int* __restrict__ deg, int nN)
{
    __shared__ int sums[1024];
    const int t = threadIdx.x;
    const int len = (nN + 1023) / 1024;
    const int lo = t * len;
    const int hi = min(nN, lo + len);
    int s = 0;
    for (int i = lo; i < hi; ++i) s += deg[i];
    sums[t] = s;
    __syncthreads();
    for (int d = 1; d < 1024; d <<= 1) {
        int v = (t >= d) ? sums[t - d] : 0;
        __syncthreads();
        sums[t] += v;
        __syncthreads();
    }
    int off = sums[t] - s;
    for (int i = lo; i < hi; ++i) {
        int d = deg[i];
        deg[i] = off;
        off += d;
    }
}

__launch_bounds__(256)
__global__ void fill_kernel(const int* __restrict__ src, const int* __restrict__ dst,
                            const float* __restrict__ w,
                            int* __restrict__ rowptr,
                            int2* __restrict__ cwp, int nE)
{
    int e = blockIdx.x * 256 + threadIdx.x;
    if (e >= nE) return;
    int d = dst[e];
    int pos = atomicAdd(&rowptr[d], 1);
    cwp[pos] = make_int2(src[e], __float_as_int(w[e]));
}

// ---------------------------------------------------------------------------
// Fused pull-SpMM + gate, bf16 propagation.  One wave per dst node (or per
// output index).
// Restructure (spmm is latency-bound: ~107us/hop vs ~20us data floor):
//   - coalesced cwp: lane l loads cwp[e0+l] -> ONE wait covers up to 64 edges
//   - (col,w) broadcast to each 16-lane channel group via __shfl
//   - 16 row-gathers issued back-to-back per block; OOB slots carry w=0 and
//     gather row 0 harmlessly (no tail loop at all)
// ---------------------------------------------------------------------------
__launch_bounds__(256)
__global__ void spmm_fused(const int* __restrict__ rowptr,
                           const int2* __restrict__ cwp,
                           const unsigned short* __restrict__ cur,
                           unsigned short* __restrict__ nxt,
                           const int* __restrict__ idx,
                           const float* __restrict__ wp,
                           float* __restrict__ out,
                           int nN, int nI, int nodeBlocks)
{
    const int bid  = blockIdx.x;
    const int wid  = threadIdx.x >> 6;
    const int lane = threadIdx.x & 63;
    const int g = lane >> 4;   // channel-group's edge sub-slot 0..3
    const int q = lane & 15;   // channel quad

    int node, oi = -1;
    if (bid < nodeBlocks) {
        node = bid * 4 + wid;
        if (node >= nN) return;
    } else {
        oi = (bid - nodeBlocks) * 4 + wid;
        if (oi >= nI) return;
        node = idx[oi];
    }

    const int beg = (node == 0) ? 0 : rowptr[node - 1];
    const int end = rowptr[node];

    float4 A0 = make_float4(0.f,0.f,0.f,0.f);
    float4 A1 = make_float4(0.f,0.f,0.f,0.f);
    float4 A2 = make_float4(0.f,0.f,0.f,0.f);
    float4 A3 = make_float4(0.f,0.f,0.f,0.f);

    for (int e0 = beg; e0 < end; e0 += 64) {
        int el = e0 + lane;
        int2 ce = make_int2(0, 0);             // col=0, w=0 for OOB slots
        if (el < end) ce = cwp[el];
        int rem = end - e0; if (rem > 64) rem = 64;

        for (int s0 = 0; s0 < rem; s0 += 16) {
            int s = s0 + g;
            int   c0 = __shfl(ce.x, s);
            float w0 = __int_as_float(__shfl(ce.y, s));
            int   c1 = __shfl(ce.x, s + 4);
            float w1 = __int_as_float(__shfl(ce.y, s + 4));
            int   c2 = __shfl(ce.x, s + 8);
            float w2 = __int_as_float(__shfl(ce.y, s + 8));
            int   c3 = __shfl(ce.x, s + 12);
            float w3 = __int_as_float(__shfl(ce.y, s + 12));
            float4 v0 = bf4(*(const ushort4*)&cur[(size_t)c0 * 64 + q * 4]);
            float4 v1 = bf4(*(const ushort4*)&cur[(size_t)c1 * 64 + q * 4]);
            float4 v2 = bf4(*(const ushort4*)&cur[(size_t)c2 * 64 + q * 4]);
            float4 v3 = bf4(*(const ushort4*)&cur[(size_t)c3 * 64 + q * 4]);
            A0.x += w0*v0.x; A0.y += w0*v0.y; A0.z += w0*v0.z; A0.w += w0*v0.w;
            A1.x += w1*v1.x; A1.y += w1*v1.y; A1.z += w1*v1.z; A1.w += w1*v1.w;
            A2.x += w2*v2.x; A2.y += w2*v2.y; A2.z += w2*v2.z; A2.w += w2*v2.w;
            A3.x += w3*v3.x; A3.y += w3*v3.y; A3.z += w3*v3.z; A3.w += w3*v3.w;
        }
    }
    A0.x += A1.x + A2.x + A3.x;
    A0.y += A1.y + A2.y + A3.y;
    A0.z += A1.z + A2.z + A3.z;
    A0.w += A1.w + A2.w + A3.w;

    // reduce across the 4 edge sub-slots (lanes differing in bits 4,5)
    A0.x += __shfl_xor(A0.x, 16); A0.y += __shfl_xor(A0.y, 16);
    A0.z += __shfl_xor(A0.z, 16); A0.w += __shfl_xor(A0.w, 16);
    A0.x += __shfl_xor(A0.x, 32); A0.y += __shfl_xor(A0.y, 32);
    A0.z += __shfl_xor(A0.z, 32); A0.w += __shfl_xor(A0.w, 32);

    if (oi < 0) {
        if (g == 0) {
            ushort4 ob = make_ushort4(f2b(A0.x), f2b(A0.y), f2b(A0.z), f2b(A0.w));
            *(ushort4*)&nxt[(size_t)node * 64 + q * 4] = ob;
        }
    } else {
        // gate: s = row . wp  (reduce partial dot across the 16 q-lanes)
        float s = A0.x * wp[q * 4] + A0.y * wp[q * 4 + 1]
                + A0.z * wp[q * 4 + 2] + A0.w * wp[q * 4 + 3];
        s += __shfl_xor(s, 1); s += __shfl_xor(s, 2);
        s += __shfl_xor(s, 4); s += __shfl_xor(s, 8);
        float gate = 1.f / (1.f + __expf(-s));
        if (g == 0) {
            float* op = &out[(size_t)oi * 64 + q * 4];
            float4 prev = *(float4*)op;
            prev.x += gate * A0.x; prev.y += gate * A0.y;
            prev.z += gate * A0.z; prev.w += gate * A0.w;
            *(float4*)op = prev;
        }
    }
}

// ---------------------------------------------------------------------------
// Hop-0 gate: out[i] = sigmoid(h[idx[i]].wp) * h[idx[i]]  (fp32 h, inits out)
// ---------------------------------------------------------------------------
__launch_bounds__(256)
__global__ void gate_gather(const float* __restrict__ h,
                            const int* __restrict__ idx,
                            const float* __restrict__ wp,
                            float* __restrict__ out, int nI)
{
    int gid = blockIdx.x * 256 + threadIdx.x;
    int i = gid >> 6;
    if (i >= nI) return;
    int c = gid & 63;
    int n = idx[i];
    float v = h[(size_t)n * 64 + c];
    float s = v * wp[c];
    #pragma unroll
    for (int off = 32; off > 0; off >>= 1)
        s += __shfl_xor(s, off);
    float gate = 1.f / (1.f + __expf(-s));
    out[gid] = gate * v;
}

extern "C" void kernel_launch(void* const* d_in, const int* in_sizes, int n_in,
                              void* d_out, int out_size, void* d_ws, size_t ws_size,
                              hipStream_t stream) {
    const float* x    = (const float*)d_in[0];
    const int*   esrc = (const int*)d_in[1];
    const int*   edst = (const int*)d_in[2];
    const float* ew   = (const float*)d_in[3];
    const int*   nidx = (const int*)d_in[4];
    const float* W1   = (const float*)d_in[5];
    const float* W2   = (const float*)d_in[6];
    const float* wp   = (const float*)d_in[7];
    float* out = (float*)d_out;

    const int nN = in_sizes[0] / 512;
    const int nE = in_sizes[1];
    const int nI = in_sizes[4];

    // ws: h0 fp32 25.6M | bufA bf16 12.8M | bufB bf16 12.8M | rowptr 0.4M | cwp 12.8M
    float*          h0     = (float*)d_ws;
    unsigned short* bufA   = (unsigned short*)(h0 + (size_t)nN * C);
    unsigned short* bufB   = bufA + (size_t)nN * C;
    int*            rowptr = (int*)(bufB + (size_t)nN * C);
    int2*           cwp    = (int2*)(rowptr + nN);

    // --- CSR build (by dst) ---
    hipMemsetAsync(rowptr, 0, (size_t)nN * sizeof(int), stream);
    count_kernel<<<(nE + 255) / 256, 256, 0, stream>>>(edst, rowptr, nE);
    scan_kernel<<<1, 1024, 0, stream>>>(rowptr, nN);
    fill_kernel<<<(nE + 255) / 256, 256, 0, stream>>>(esrc, edst, ew, rowptr, cwp, nE);

    // --- MLP (fp32 + bf16 h) ---
    mlp_kernel<<<(nN + 63) / 64, 256, 0, stream>>>(x, W1, W2, h0, bufA, nN);

    // hop 0 gate (initializes out, fp32 path)
    gate_gather<<<(nI * 64 + 255) / 256, 256, 0, stream>>>(h0, nidx, wp, out, nI);

    unsigned short* cur = bufA;
    unsigned short* nxt = bufB;
    const int nodeBlocks = (nN + 3) / 4;
    const int idxBlocks  = (nI + 3) / 4;
    for (int k = 0; k < 10; ++k) {
        // Final hop: nxt is never read again -> launch only the idx-tail
        // blocks (gate into out); skip the 25k node blocks entirely.
        const int nb = (k == 9) ? 0 : nodeBlocks;
        spmm_fused<<<nb + idxBlocks, 256, 0, stream>>>(
            rowptr, cwp, cur, nxt, nidx, wp, out, nN, nI, nb);
        unsigned short* tmp = cur; cur = nxt; nxt = tmp;
    }
}

// Round 5
// 954.196 us; speedup vs baseline: 1.3627x; 1.1378x over previous
//
#include <hip/hip_runtime.h>
#include <hip/hip_bf16.h>

#define C 64  // channels

// bf16 <-> f32 helpers (bit-level, RNE on pack)
__device__ __forceinline__ float b2f(unsigned short s) {
    return __uint_as_float(((unsigned int)s) << 16);
}
__device__ __forceinline__ unsigned short f2b(float f) {
    unsigned int u = __float_as_uint(f);
    u = (u + 0x7FFF + ((u >> 16) & 1)) >> 16;
    return (unsigned short)u;
}

// ---------------------------------------------------------------------------
// Fused MLP: h = relu(relu(x @ W1) @ W2).
// Writes BOTH fp32 h0 (hop-0 gate) and bf16 hb (propagation seed).
// BK=64 single-buffered, direct global->LDS staging (NO long-lived prefetch
// registers -- R1's reg-prefetch spilled: VGPR 92->68, WRITE_SIZE 190MB).
// Verified R4: 162us, VALUBusy 48%, WRITE_SIZE 37.5MB, VGPR 64.
// ---------------------------------------------------------------------------
__launch_bounds__(256)
__global__ void mlp_kernel(const float* __restrict__ x,
                           const float* __restrict__ W1,
                           const float* __restrict__ W2,
                           float* __restrict__ h0,
                           unsigned short* __restrict__ hb, int nN)
{
    __shared__ float smem[8704];
    float (*As)[68] = (float(*)[68])smem;            // 64 x 68
    float (*Bs)[68] = (float(*)[68])(smem + 4352);   // 64 x 68
    float (*Hs)[68] = (float(*)[68])smem;            // GEMM2 reuse
    float (*Ws)[68] = (float(*)[68])(smem + 4352);

    const int t  = threadIdx.x;
    const int ty = t >> 4;
    const int tx = t & 15;
    const int row0 = blockIdx.x * 64;

    const int srow = t >> 4;
    const int slk  = (t & 15) * 4;

    float acc[4][4] = {};

    for (int k0 = 0; k0 < 512; k0 += 64) {
        #pragma unroll
        for (int h = 0; h < 4; ++h) {
            int r = srow + 16 * h;
            int grow = row0 + r;
            float4 v = make_float4(0.f, 0.f, 0.f, 0.f);
            if (grow < nN) v = *(const float4*)&x[(size_t)grow * 512 + k0 + slk];
            *(float4*)&As[r][slk] = v;
        }
        #pragma unroll
        for (int h = 0; h < 4; ++h) {
            int r = srow + 16 * h;
            *(float4*)&Bs[r][slk] = *(const float4*)&W1[(size_t)(k0 + r) * 64 + slk];
        }
        __syncthreads();

        for (int kk = 0; kk < 64; kk += 4) {
            float4 b0 = *(float4*)&Bs[kk + 0][tx * 4];
            float4 b1 = *(float4*)&Bs[kk + 1][tx * 4];
            float4 b2 = *(float4*)&Bs[kk + 2][tx * 4];
            float4 b3 = *(float4*)&Bs[kk + 3][tx * 4];
            #pragma unroll
            for (int i = 0; i < 4; ++i) {
                float4 a = *(float4*)&As[ty * 4 + i][kk];
                acc[i][0] += a.x * b0.x + a.y * b1.x + a.z * b2.x + a.w * b3.x;
                acc[i][1] += a.x * b0.y + a.y * b1.y + a.z * b2.y + a.w * b3.y;
                acc[i][2] += a.x * b0.z + a.y * b1.z + a.z * b2.z + a.w * b3.z;
                acc[i][3] += a.x * b0.w + a.y * b1.w + a.z * b2.w + a.w * b3.w;
            }
        }
        __syncthreads();
    }

    #pragma unroll
    for (int i = 0; i < 4; ++i) {
        float4 o;
        o.x = acc[i][0] > 0.f ? acc[i][0] : 0.f;
        o.y = acc[i][1] > 0.f ? acc[i][1] : 0.f;
        o.z = acc[i][2] > 0.f ? acc[i][2] : 0.f;
        o.w = acc[i][3] > 0.f ? acc[i][3] : 0.f;
        *(float4*)&Hs[ty * 4 + i][tx * 4] = o;
    }
    #pragma unroll
    for (int qq = 0; qq < 4; ++qq) {
        int r = srow + 16 * qq;
        *(float4*)&Ws[r][slk] = *(const float4*)&W2[(size_t)r * 64 + slk];
    }
    __syncthreads();

    float acc2[4][4] = {};
    for (int kk = 0; kk < 64; kk += 4) {
        float4 b0 = *(float4*)&Ws[kk + 0][tx * 4];
        float4 b1 = *(float4*)&Ws[kk + 1][tx * 4];
        float4 b2 = *(float4*)&Ws[kk + 2][tx * 4];
        float4 b3 = *(float4*)&Ws[kk + 3][tx * 4];
        #pragma unroll
        for (int i = 0; i < 4; ++i) {
            float4 a = *(float4*)&Hs[ty * 4 + i][kk];
            acc2[i][0] += a.x * b0.x + a.y * b1.x + a.z * b2.x + a.w * b3.x;
            acc2[i][1] += a.x * b0.y + a.y * b1.y + a.z * b2.y + a.w * b3.y;
            acc2[i][2] += a.x * b0.z + a.y * b1.z + a.z * b2.z + a.w * b3.z;
            acc2[i][3] += a.x * b0.w + a.y * b1.w + a.z * b2.w + a.w * b3.w;
        }
    }

    #pragma unroll
    for (int i = 0; i < 4; ++i) {
        int grow = row0 + ty * 4 + i;
        if (grow < nN) {
            float4 o;
            o.x = acc2[i][0] > 0.f ? acc2[i][0] : 0.f;
            o.y = acc2[i][1] > 0.f ? acc2[i][1] : 0.f;
            o.z = acc2[i][2] > 0.f ? acc2[i][2] : 0.f;
            o.w = acc2[i][3] > 0.f ? acc2[i][3] : 0.f;
            *(float4*)&h0[(size_t)grow * 64 + tx * 4] = o;
            ushort4 ob = make_ushort4(f2b(o.x), f2b(o.y), f2b(o.z), f2b(o.w));
            *(ushort4*)&hb[(size_t)grow * 64 + tx * 4] = ob;
        }
    }
}

// ---------------------------------------------------------------------------
// CSR build: degree count -> HIERARCHICAL scan -> atomic fill.
// R5: the old single-block scan_kernel was 163us (one CU, serial walk).
// Replaced with 3 kernels: per-block scan (1024 elems/block) + block-sum
// scan (<=256 blocks) + offset add.  Block sums live in bufB (dead until
// the first spmm writes nxt).  Expected ~8us total.
// After fill, rowptr[n] = END offset; start = rowptr[n-1] (0 for n=0).
// ---------------------------------------------------------------------------
__launch_bounds__(256)
__global__ void count_kernel(const int* __restrict__ dst, int* __restrict__ rowptr, int nE)
{
    int e = blockIdx.x * 256 + threadIdx.x;
    if (e < nE) atomicAdd(&rowptr[dst[e]], 1);
}

// per-block exclusive scan of 1024 elements (256 thr x 4), block total -> bsum
__launch_bounds__(256)
__global__ void scanA(int* __restrict__ deg, int* __restrict__ bsum, int nN)
{
    __shared__ int ts[256];
    const int t = threadIdx.x;
    const int base = blockIdx.x * 1024 + t * 4;
    int v0 = 0, v1 = 0, v2 = 0, v3 = 0;
    if (base + 3 < nN) {
        int4 v = *(const int4*)&deg[base];
        v0 = v.x; v1 = v.y; v2 = v.z; v3 = v.w;
    } else {
        if (base + 0 < nN) v0 = deg[base + 0];
        if (base + 1 < nN) v1 = deg[base + 1];
        if (base + 2 < nN) v2 = deg[base + 2];
        if (base + 3 < nN) v3 = deg[base + 3];
    }
    int s = v0 + v1 + v2 + v3;
    ts[t] = s;
    __syncthreads();
    for (int d = 1; d < 256; d <<= 1) {
        int xv = (t >= d) ? ts[t - d] : 0;
        __syncthreads();
        ts[t] += xv;
        __syncthreads();
    }
    if (t == 255) bsum[blockIdx.x] = ts[255];
    int e0 = ts[t] - s;      // exclusive within block
    int e1 = e0 + v0;
    int e2 = e1 + v1;
    int e3 = e2 + v2;
    if (base + 3 < nN) {
        *(int4*)&deg[base] = make_int4(e0, e1, e2, e3);
    } else {
        if (base + 0 < nN) deg[base + 0] = e0;
        if (base + 1 < nN) deg[base + 1] = e1;
        if (base + 2 < nN) deg[base + 2] = e2;
        if (base + 3 < nN) deg[base + 3] = e3;
    }
}

// exclusive scan of up to 256 block sums, in place
__launch_bounds__(256)
__global__ void scanB(int* __restrict__ bsum, int nB)
{
    __shared__ int ts[256];
    const int t = threadIdx.x;
    int v = (t < nB) ? bsum[t] : 0;
    ts[t] = v;
    __syncthreads();
    for (int d = 1; d < 256; d <<= 1) {
        int xv = (t >= d) ? ts[t - d] : 0;
        __syncthreads();
        ts[t] += xv;
        __syncthreads();
    }
    if (t < nB) bsum[t] = ts[t] - v;
}

// add scanned block sums back
__launch_bounds__(256)
__global__ void scanC(int* __restrict__ deg, const int* __restrict__ bsum, int nN)
{
    const int i4 = (blockIdx.x * 256 + threadIdx.x) * 4;
    if (i4 >= nN) return;
    const int b = bsum[i4 >> 10];
    if (i4 + 3 < nN) {
        int4 v = *(int4*)&deg[i4];
        v.x += b; v.y += b; v.z += b; v.w += b;
        *(int4*)&deg[i4] = v;
    } else {
        for (int j = 0; j < 4 && i4 + j < nN; ++j) deg[i4 + j] += b;
    }
}

__launch_bounds__(256)
__global__ void fill_kernel(const int* __restrict__ src, const int* __restrict__ dst,
                            const float* __restrict__ w,
                            int* __restrict__ rowptr,
                            int2* __restrict__ cwp, int nE)
{
    int e = blockIdx.x * 256 + threadIdx.x;
    if (e >= nE) return;
    int d = dst[e];
    int pos = atomicAdd(&rowptr[d], 1);
    cwp[pos] = make_int2(src[e], __float_as_int(w[e]));
}

// ---------------------------------------------------------------------------
// Fused pull-SpMM + gate, bf16 propagation.  One wave per dst node (or per
// output index).
// R5 shape: 8 edge sub-slots x 8 lanes x int4 (16B = 8 bf16 ch per lane).
// Halves gather + shfl instruction count vs the 16-lane/8B shape at equal
// traffic.  Coalesced cwp (lane l loads cwp[e0+l], one wait per 64 edges);
// OOB slots carry w=0, col=0 (harmless row-0 gather); no tail loop.
// ---------------------------------------------------------------------------
__launch_bounds__(256)
__global__ void spmm_fused(const int* __restrict__ rowptr,
                           const int2* __restrict__ cwp,
                           const unsigned short* __restrict__ cur,
                           unsigned short* __restrict__ nxt,
                           const int* __restrict__ idx,
                           const float* __restrict__ wp,
                           float* __restrict__ out,
                           int nN, int nI, int nodeBlocks)
{
    const int bid  = blockIdx.x;
    const int wid  = threadIdx.x >> 6;
    const int lane = threadIdx.x & 63;
    const int g = lane >> 3;   // edge sub-slot 0..7
    const int q = lane & 7;    // channel octet (8 bf16 = 16B)

    int node, oi = -1;
    if (bid < nodeBlocks) {
        node = bid * 4 + wid;
        if (node >= nN) return;
    } else {
        oi = (bid - nodeBlocks) * 4 + wid;
        if (oi >= nI) return;
        node = idx[oi];
    }

    const int beg = (node == 0) ? 0 : rowptr[node - 1];
    const int end = rowptr[node];

    float a0[8] = {}, a1[8] = {};

    for (int e0 = beg; e0 < end; e0 += 64) {
        int el = e0 + lane;
        int2 ce = make_int2(0, 0);             // col=0, w=0 for OOB slots
        if (el < end) ce = cwp[el];
        int rem = end - e0; if (rem > 64) rem = 64;

        for (int s0 = 0; s0 < rem; s0 += 16) {
            int s = s0 + g;                     // s <= 55, s+8 <= 63
            int   c0 = __shfl(ce.x, s);
            float w0 = __int_as_float(__shfl(ce.y, s));
            int   c1 = __shfl(ce.x, s + 8);
            float w1 = __int_as_float(__shfl(ce.y, s + 8));
            int4 r0 = *(const int4*)&cur[(size_t)c0 * 64 + q * 8];
            int4 r1 = *(const int4*)&cur[(size_t)c1 * 64 + q * 8];
            a0[0] += w0 * __uint_as_float((unsigned)r0.x << 16);
            a0[1] += w0 * __uint_as_float((unsigned)r0.x & 0xFFFF0000u);
            a0[2] += w0 * __uint_as_float((unsigned)r0.y << 16);
            a0[3] += w0 * __uint_as_float((unsigned)r0.y & 0xFFFF0000u);
            a0[4] += w0 * __uint_as_float((unsigned)r0.z << 16);
            a0[5] += w0 * __uint_as_float((unsigned)r0.z & 0xFFFF0000u);
            a0[6] += w0 * __uint_as_float((unsigned)r0.w << 16);
            a0[7] += w0 * __uint_as_float((unsigned)r0.w & 0xFFFF0000u);
            a1[0] += w1 * __uint_as_float((unsigned)r1.x << 16);
            a1[1] += w1 * __uint_as_float((unsigned)r1.x & 0xFFFF0000u);
            a1[2] += w1 * __uint_as_float((unsigned)r1.y << 16);
            a1[3] += w1 * __uint_as_float((unsigned)r1.y & 0xFFFF0000u);
            a1[4] += w1 * __uint_as_float((unsigned)r1.z << 16);
            a1[5] += w1 * __uint_as_float((unsigned)r1.z & 0xFFFF0000u);
            a1[6] += w1 * __uint_as_float((unsigned)r1.w << 16);
            a1[7] += w1 * __uint_as_float((unsigned)r1.w & 0xFFFF0000u);
        }
    }
    #pragma unroll
    for (int j = 0; j < 8; ++j) a0[j] += a1[j];

    // reduce across the 8 edge sub-slots (lane bits 3,4,5)
    #pragma unroll
    for (int j = 0; j < 8; ++j) {
        a0[j] += __shfl_xor(a0[j], 8);
        a0[j] += __shfl_xor(a0[j], 16);
        a0[j] += __shfl_xor(a0[j], 32);
    }

    if (oi < 0) {
        if (g == 0) {
            int4 ob;
            ob.x = (int)(((unsigned)f2b(a0[1]) << 16) | (unsigned)f2b(a0[0]));
            ob.y = (int)(((unsigned)f2b(a0[3]) << 16) | (unsigned)f2b(a0[2]));
            ob.z = (int)(((unsigned)f2b(a0[5]) << 16) | (unsigned)f2b(a0[4]));
            ob.w = (int)(((unsigned)f2b(a0[7]) << 16) | (unsigned)f2b(a0[6]));
            *(int4*)&nxt[(size_t)node * 64 + q * 8] = ob;
        }
    } else {
        // gate: s = row . wp  (partial dot over this lane's 8 ch, then
        // reduce across the 8 q-lanes = lane bits 0,1,2)
        float s = 0.f;
        #pragma unroll
        for (int j = 0; j < 8; ++j) s += a0[j] * wp[q * 8 + j];
        s += __shfl_xor(s, 1); s += __shfl_xor(s, 2); s += __shfl_xor(s, 4);
        float gate = 1.f / (1.f + __expf(-s));
        if (g == 0) {
            float* op = &out[(size_t)oi * 64 + q * 8];
            float4 p0 = *(float4*)op;
            float4 p1 = *(float4*)(op + 4);
            p0.x += gate * a0[0]; p0.y += gate * a0[1];
            p0.z += gate * a0[2]; p0.w += gate * a0[3];
            p1.x += gate * a0[4]; p1.y += gate * a0[5];
            p1.z += gate * a0[6]; p1.w += gate * a0[7];
            *(float4*)op = p0;
            *(float4*)(op + 4) = p1;
        }
    }
}

// ---------------------------------------------------------------------------
// Hop-0 gate: out[i] = sigmoid(h[idx[i]].wp) * h[idx[i]]  (fp32 h, inits out)
// ---------------------------------------------------------------------------
__launch_bounds__(256)
__global__ void gate_gather(const float* __restrict__ h,
                            const int* __restrict__ idx,
                            const float* __restrict__ wp,
                            float* __restrict__ out, int nI)
{
    int gid = blockIdx.x * 256 + threadIdx.x;
    int i = gid >> 6;
    if (i >= nI) return;
    int c = gid & 63;
    int n = idx[i];
    float v = h[(size_t)n * 64 + c];
    float s = v * wp[c];
    #pragma unroll
    for (int off = 32; off > 0; off >>= 1)
        s += __shfl_xor(s, off);
    float gate = 1.f / (1.f + __expf(-s));
    out[gid] = gate * v;
}

extern "C" void kernel_launch(void* const* d_in, const int* in_sizes, int n_in,
                              void* d_out, int out_size, void* d_ws, size_t ws_size,
                              hipStream_t stream) {
    const float* x    = (const float*)d_in[0];
    const int*   esrc = (const int*)d_in[1];
    const int*   edst = (const int*)d_in[2];
    const float* ew   = (const float*)d_in[3];
    const int*   nidx = (const int*)d_in[4];
    const float* W1   = (const float*)d_in[5];
    const float* W2   = (const float*)d_in[6];
    const float* wp   = (const float*)d_in[7];
    float* out = (float*)d_out;

    const int nN = in_sizes[0] / 512;
    const int nE = in_sizes[1];
    const int nI = in_sizes[4];

    // ws: h0 fp32 25.6M | bufA bf16 12.8M | bufB bf16 12.8M | rowptr 0.4M | cwp 12.8M
    float*          h0     = (float*)d_ws;
    unsigned short* bufA   = (unsigned short*)(h0 + (size_t)nN * C);
    unsigned short* bufB   = bufA + (size_t)nN * C;
    int*            rowptr = (int*)(bufB + (size_t)nN * C);
    int2*           cwp    = (int2*)(rowptr + nN);
    // block sums for the hierarchical scan: bufB is dead until the first
    // spmm writes nxt, so borrow its head as scratch.
    int*            bsum   = (int*)bufB;

    const int nB = (nN + 1023) / 1024;   // <= 256 for nN <= 262144

    // --- CSR build (by dst) ---
    hipMemsetAsync(rowptr, 0, (size_t)nN * sizeof(int), stream);
    count_kernel<<<(nE + 255) / 256, 256, 0, stream>>>(edst, rowptr, nE);
    scanA<<<nB, 256, 0, stream>>>(rowptr, bsum, nN);
    scanB<<<1, 256, 0, stream>>>(bsum, nB);
    scanC<<<nB, 256, 0, stream>>>(rowptr, bsum, nN);
    fill_kernel<<<(nE + 255) / 256, 256, 0, stream>>>(esrc, edst, ew, rowptr, cwp, nE);

    // --- MLP (fp32 + bf16 h) ---
    mlp_kernel<<<(nN + 63) / 64, 256, 0, stream>>>(x, W1, W2, h0, bufA, nN);

    // hop 0 gate (initializes out, fp32 path)
    gate_gather<<<(nI * 64 + 255) / 256, 256, 0, stream>>>(h0, nidx, wp, out, nI);

    unsigned short* cur = bufA;
    unsigned short* nxt = bufB;
    const int nodeBlocks = (nN + 3) / 4;
    const int idxBlocks  = (nI + 3) / 4;
    for (int k = 0; k < 10; ++k) {
        // Final hop: nxt is never read again -> launch only the idx-tail
        // blocks (gate into out); skip the 25k node blocks entirely.
        const int nb = (k == 9) ? 0 : nodeBlocks;
        spmm_fused<<<nb + idxBlocks, 256, 0, stream>>>(
            rowptr, cwp, cur, nxt, nidx, wp, out, nN, nI, nb);
        unsigned short* tmp = cur; cur = nxt; nxt = tmp;
    }
}